// Round 3
// baseline (115.624 us; speedup 1.0000x reference)
//
#include <hip/hip_runtime.h>
#include <hip/hip_bf16.h>
#include <stdint.h>

#define B_   512
#define C_   440
#define CR_  52
#define HW_  49
#define KP_  448          // padded K (=C) to multiple of 32
#define OP_  512          // padded O (=C) to multiple of 128
#define M_   25088        // B_*HW_ (= 196*128 exactly)
#define TS_  456          // LDS transpose row stride (multiple of 8, breaks pow2)

typedef __attribute__((ext_vector_type(8))) short bf8;
typedef __attribute__((ext_vector_type(4))) float f4;

__device__ __forceinline__ unsigned short f2bf(float f) {
  union { float f; unsigned u; } v; v.f = f;
  unsigned r = v.u + 0x7FFFu + ((v.u >> 16) & 1u);
  return (unsigned short)(r >> 16);
}

__device__ __forceinline__ void gld16(const void* g, void* l) {
  __builtin_amdgcn_global_load_lds(
      (const __attribute__((address_space(1))) unsigned int*)g,
      (__attribute__((address_space(3))) unsigned int*)l, 16, 0, 0);
}

// ---------------- K1: w3 fp32 -> bf16, padded [OP_][KP_] ----------------
__global__ __launch_bounds__(256) void k_prep_w3(const float* __restrict__ w3,
                                                 unsigned short* __restrict__ w3bf) {
  int idx = blockIdx.x * 256 + threadIdx.x;      // grid covers 512*448 exactly
  int o = idx / KP_, c = idx - o * KP_;
  float v = (c < C_ && o < C_) ? w3[o * C_ + c] : 0.f;
  w3bf[idx] = f2bf(v);
}

// ------- K2: per-b gate MLP + gating + transpose to gbf[m][KP_] bf16 -------
__global__ __launch_bounds__(256) void k_gate_transpose(
    const float* __restrict__ x178, const float* __restrict__ x177,
    const float* __restrict__ w1, const float* __restrict__ b1,
    const float* __restrict__ w2, const float* __restrict__ b2,
    unsigned short* __restrict__ gbf) {
  __shared__ float s_s[C_];
  __shared__ float s_h[CR_];
  __shared__ float s_gate[C_];
  __shared__ __align__(16) unsigned short s_t[HW_ * TS_];
  int b = blockIdx.x, tid = threadIdx.x;
  int lane = tid & 63, wv = tid >> 6;

  for (int c = tid; c < C_; c += 256) s_s[c] = x178[b * C_ + c];
  __syncthreads();

  // h = relu(s @ w1^T + b1)   (wave-parallel: wave wv handles rows wv,wv+4,...)
  for (int r = wv; r < CR_; r += 4) {
    float acc = 0.f;
    for (int c = lane; c < C_; c += 64) acc += s_s[c] * w1[r * C_ + c];
    #pragma unroll
    for (int off = 32; off; off >>= 1) acc += __shfl_xor(acc, off, 64);
    if (lane == 0) s_h[r] = fmaxf(acc + b1[r], 0.f);
  }
  __syncthreads();

  // gate = sigmoid(h @ w2^T + b2)
  for (int c = tid; c < C_; c += 256) {
    float acc = b2[c];
    #pragma unroll 4
    for (int r = 0; r < CR_; ++r) acc += s_h[r] * w2[c * CR_ + r];
    s_gate[c] = 1.f / (1.f + __expf(-acc));
  }
  __syncthreads();

  // gated = x177[b] * gate, transposed into LDS [hw][c] as bf16
  const float* xp = x177 + (size_t)b * (C_ * HW_);
  for (int idx = tid; idx < C_ * HW_; idx += 256) {
    int c = idx / HW_, hw = idx - c * HW_;
    s_t[hw * TS_ + c] = f2bf(xp[idx] * s_gate[c]);
  }
  // zero K-pad columns 440..447
  for (int z = tid; z < HW_ * 8; z += 256) {
    int hw = z >> 3, c = C_ + (z & 7);
    s_t[hw * TS_ + c] = 0;
  }
  __syncthreads();

  // write out: gbf[(b*49+hw)][c], 16B chunks, coalesced
  unsigned short* gp = gbf + (size_t)b * HW_ * KP_;
  for (int p = tid; p < HW_ * (KP_ / 8); p += 256) {
    int hw = p / (KP_ / 8), cg = p - hw * (KP_ / 8);
    *(bf8*)(gp + hw * KP_ + cg * 8) = *(const bf8*)(s_t + hw * TS_ + cg * 8);
  }
}

// ---------------- K3: y[o][m] = sum_c w3[o][c] * g[m][c]  (bf16 MFMA) ----------------
__global__ __launch_bounds__(256) void k_gemm(const unsigned short* __restrict__ w3bf,
                                              const unsigned short* __restrict__ gbf,
                                              float* __restrict__ y) {
  __shared__ __align__(16) unsigned short lds[2 * 128 * 32];  // A tile | B tile
  int tid = threadIdx.x, lane = tid & 63, wv = tid >> 6;
  int bid = blockIdx.x;
  int o0 = (bid & 3) * 128;        // 4 o-tiles (OP_=512)
  int m0 = (bid >> 2) * 128;       // 196 m-tiles
  int wr = wv >> 1, wc = wv & 1;   // wave -> 64x64 quadrant
  f4 acc[4][4] = {};
  const char* Ab = (const char*)w3bf;  // row stride 896 B
  const char* Bb = (const char*)gbf;   // row stride 896 B
  int q0 = wv * 64 + lane;

  for (int kt = 0; kt < KP_ / 32; ++kt) {
    int k0b = kt * 64;  // byte offset of k0 within a row
    #pragma unroll
    for (int i = 0; i < 2; ++i) {
      int q = q0 + i * 256;
      int r = q >> 2, cc = (q & 3) * 16;
      gld16(Ab + (size_t)(o0 + r) * 896 + k0b + cc,
            (char*)lds + (wv * 64 + i * 256) * 16);
      gld16(Bb + (size_t)(m0 + r) * 896 + k0b + cc,
            (char*)lds + 8192 + (wv * 64 + i * 256) * 16);
    }
    __syncthreads();   // compiler drains vmcnt before barrier

    bf8 a[4], bb[4];
    int kg = (lane >> 4) * 8, rl = lane & 15;
    #pragma unroll
    for (int i = 0; i < 4; ++i)
      a[i] = *(const bf8*)(lds + (wr * 64 + i * 16 + rl) * 32 + kg);
    #pragma unroll
    for (int j = 0; j < 4; ++j)
      bb[j] = *(const bf8*)(lds + 4096 + (wc * 64 + j * 16 + rl) * 32 + kg);
    #pragma unroll
    for (int i = 0; i < 4; ++i)
      #pragma unroll
      for (int j = 0; j < 4; ++j)
        acc[i][j] = __builtin_amdgcn_mfma_f32_16x16x32_bf16(a[i], bb[j], acc[i][j], 0, 0, 0);
    __syncthreads();
  }

  // D layout: col = lane&15 (m), row = (lane>>4)*4 + reg (o)
  int col = lane & 15, r4 = (lane >> 4) * 4;
  #pragma unroll
  for (int i = 0; i < 4; ++i) {
    int ob = o0 + wr * 64 + i * 16 + r4;
    #pragma unroll
    for (int j = 0; j < 4; ++j) {
      int m = m0 + wc * 64 + j * 16 + col;
      #pragma unroll
      for (int r = 0; r < 4; ++r) {
        int o = ob + r;
        if (o < C_) y[(size_t)o * M_ + m] = acc[i][j][r];
      }
    }
  }
}

// ---------------- K4: per-channel mean/var + normalize + scatter ----------------
__global__ __launch_bounds__(256) void k_norm(const float* __restrict__ y,
                                              const float* __restrict__ gamma,
                                              const float* __restrict__ beta,
                                              float* __restrict__ out) {
  __shared__ float rs[4], rq[4];
  __shared__ float s_scale, s_shift;
  int o = blockIdx.x, tid = threadIdx.x, lane = tid & 63, wv = tid >> 6;
  const float4* yr = (const float4*)(y + (size_t)o * M_);
  float sum = 0.f, sq = 0.f;
  for (int i = tid; i < M_ / 4; i += 256) {
    float4 v = yr[i];
    sum += v.x + v.y + v.z + v.w;
    sq  += v.x * v.x + v.y * v.y + v.z * v.z + v.w * v.w;
  }
  #pragma unroll
  for (int off = 32; off; off >>= 1) {
    sum += __shfl_xor(sum, off, 64);
    sq  += __shfl_xor(sq,  off, 64);
  }
  if (lane == 0) { rs[wv] = sum; rq[wv] = sq; }
  __syncthreads();
  if (tid == 0) {
    float S = rs[0] + rs[1] + rs[2] + rs[3];
    float Q = rq[0] + rq[1] + rq[2] + rq[3];
    float mean = S / (float)M_;
    float var  = Q / (float)M_ - mean * mean;
    float sc = gamma[o] * rsqrtf(var + 1e-5f);
    s_scale = sc;
    s_shift = beta[o] - mean * sc;
  }
  __syncthreads();
  float sc = s_scale, sh = s_shift;
  for (int i = tid; i < M_ / 4; i += 256) {
    float4 v = yr[i];
    float vals[4] = {v.x * sc + sh, v.y * sc + sh, v.z * sc + sh, v.w * sc + sh};
    int m = i * 4;
    #pragma unroll
    for (int j = 0; j < 4; ++j) {
      int mm = m + j;
      int bb = mm / HW_, hw = mm - bb * HW_;
      out[(size_t)bb * (C_ * HW_) + o * HW_ + hw] = vals[j];
    }
  }
}

extern "C" void kernel_launch(void* const* d_in, const int* in_sizes, int n_in,
                              void* d_out, int out_size, void* d_ws, size_t ws_size,
                              hipStream_t stream) {
  const float* x178 = (const float*)d_in[0];
  const float* x177 = (const float*)d_in[1];
  const float* w1   = (const float*)d_in[2];
  const float* b1   = (const float*)d_in[3];
  const float* w2   = (const float*)d_in[4];
  const float* b2   = (const float*)d_in[5];
  const float* w3   = (const float*)d_in[6];
  const float* gamma= (const float*)d_in[7];
  const float* beta = (const float*)d_in[8];
  float* out = (float*)d_out;

  char* ws = (char*)d_ws;
  unsigned short* w3bf = (unsigned short*)ws;                        // 512*448*2 = 458752
  unsigned short* gbf  = (unsigned short*)(ws + 458752);             // 25088*448*2 = 22478848
  float* y             = (float*)(ws + 458752 + 22478848);           // 440*25088*4 = 44154880

  hipLaunchKernelGGL(k_prep_w3, dim3((OP_ * KP_) / 256), dim3(256), 0, stream, w3, w3bf);
  hipLaunchKernelGGL(k_gate_transpose, dim3(B_), dim3(256), 0, stream,
                     x178, x177, w1, b1, w2, b2, gbf);
  hipLaunchKernelGGL(k_gemm, dim3((M_ / 128) * (OP_ / 128)), dim3(256), 0, stream,
                     w3bf, gbf, y);
  hipLaunchKernelGGL(k_norm, dim3(C_), dim3(256), 0, stream, y, gamma, beta, out);
}